// Round 2
// baseline (560.494 us; speedup 1.0000x reference)
//
#include <hip/hip_runtime.h>
#include <hip/hip_bf16.h>

using bf16 = __hip_bfloat16;

constexpr int B = 4, T = 1024, K = 3, N = 4, H = 12, D = 64, O3 = 192;

__device__ __forceinline__ float bflo(unsigned u) { return __uint_as_float(u << 16); }
__device__ __forceinline__ float bfhi(unsigned u) { return __uint_as_float(u & 0xffff0000u); }

// Kernel 1: routed QKV projection (fp32 inputs).
// qkv[b,t,k,n,:] = x[b,t,k,n,:] @ Wqkv[k, s2h[k,n], :, :]   (routing folded into weight index)
// Writes q,k,v as bf16 [B*H, T, D] into workspace.
__global__ __launch_bounds__(192) void proj_kernel(
    const float* __restrict__ x, const float* __restrict__ W,
    const int* __restrict__ s2h,
    bf16* __restrict__ qw, bf16* __restrict__ kw, bf16* __restrict__ vw)
{
    __shared__ float lw[D * O3];   // 48 KB: W' tile
    __shared__ float lx[64 * D];   // 16 KB: x tile (64 t's)
    const int bh = blockIdx.y;
    const int b = bh / H, h = bh % H;
    const int kk = h / N;
    const int m = s2h[h];                       // s2h flat [K][N], h = kk*N+n
    const float* Wp = W + (size_t)(kk * N + m) * D * O3;
    const int tid = threadIdx.x;
    for (int e4 = tid; e4 < D * O3 / 4; e4 += 192) {
        reinterpret_cast<float4*>(lw)[e4] = reinterpret_cast<const float4*>(Wp)[e4];
    }
    const int t0 = blockIdx.x * 64;
    const float* xp = x + ((size_t)(b * T + t0) * H + h) * D;
    for (int e4 = tid; e4 < 64 * D / 4; e4 += 192) {
        int tt = e4 >> 4, j = e4 & 15;          // 16 float4 per 64-elem row
        reinterpret_cast<float4*>(lx)[e4] =
            reinterpret_cast<const float4*>(xp + (size_t)tt * H * D)[j];
    }
    __syncthreads();
    const int o = tid;                          // output column 0..191
    float wcol[D];
    #pragma unroll
    for (int i = 0; i < D; ++i) wcol[i] = lw[i * O3 + o];
    const int part = o >> 6, d = o & 63;        // part: 0=q,1=k,2=v
    bf16* outp = (part == 0 ? qw : part == 1 ? kw : vw) + ((size_t)bh * T + t0) * D + d;
    for (int tt = 0; tt < 64; ++tt) {
        const float4* xr = reinterpret_cast<const float4*>(&lx[tt * D]);
        float acc = 0.f;
        #pragma unroll
        for (int i4 = 0; i4 < 16; ++i4) {
            float4 xv = xr[i4];                  // broadcast across wave: free
            acc += xv.x * wcol[4*i4]   + xv.y * wcol[4*i4+1]
                 + xv.z * wcol[4*i4+2] + xv.w * wcol[4*i4+3];
        }
        outp[(size_t)tt * D] = __float2bfloat16(acc);
    }
}

// Kernel 2: causal flash attention per (b,h, 64-row q-tile). fp32 output.
// 256 threads = 64 q-rows (r = tid&63) x 4 column groups (c = tid>>6).
__global__ __launch_bounds__(256) void attn_kernel(
    const bf16* __restrict__ qw, const bf16* __restrict__ kw,
    const bf16* __restrict__ vw, float* __restrict__ out)
{
    __shared__ float lk[64 * D];      // 16 KB  (row-major, reads are wave-broadcast)
    __shared__ float lv[64 * D];      // 16 KB
    __shared__ float lp[64 * 65];     // probs, pad 65 -> 2-way bank access (free)
    __shared__ float redm[64 * 5];
    __shared__ float redl[64 * 5];

    const int idx = blockIdx.x;
    const int bh = idx % (B * H);
    const int qi = idx / (B * H);
    // bijective perm of 0..15 mixing heavy/light q-tiles across the dispatch order
    const int qt = (qi & 1) ? (qi >> 1) : (15 - (qi >> 1));
    const int b = bh / H, h = bh % H;
    const int tid = threadIdx.x;
    const int r = tid & 63, c = tid >> 6;
    const int tq = qt * 64 + r;

    float qreg[D];
    {
        const uint4* qp = reinterpret_cast<const uint4*>(qw + ((size_t)bh * T + tq) * D);
        #pragma unroll
        for (int j = 0; j < 8; ++j) {
            uint4 u = qp[j];
            qreg[8*j+0] = bflo(u.x) * 0.125f; qreg[8*j+1] = bfhi(u.x) * 0.125f;
            qreg[8*j+2] = bflo(u.y) * 0.125f; qreg[8*j+3] = bfhi(u.y) * 0.125f;
            qreg[8*j+4] = bflo(u.z) * 0.125f; qreg[8*j+5] = bfhi(u.z) * 0.125f;
            qreg[8*j+6] = bflo(u.w) * 0.125f; qreg[8*j+7] = bfhi(u.w) * 0.125f;
        }
    }
    float oacc[16];
    #pragma unroll
    for (int d = 0; d < 16; ++d) oacc[d] = 0.f;
    float m_old = -1e30f, l_old = 0.f;

    for (int st = 0; st <= qt; ++st) {
        __syncthreads();   // prior iteration's PV reads of lk/lv/lp complete
        const bf16* kp = kw + ((size_t)bh * T + st * 64) * D;
        const bf16* vp = vw + ((size_t)bh * T + st * 64) * D;
        for (int e4 = tid; e4 < 64 * D / 4; e4 += 256) {
            uint2 uk = reinterpret_cast<const uint2*>(kp)[e4];
            uint2 uv = reinterpret_cast<const uint2*>(vp)[e4];
            int e = e4 * 4;
            lk[e] = bflo(uk.x); lk[e+1] = bfhi(uk.x); lk[e+2] = bflo(uk.y); lk[e+3] = bfhi(uk.y);
            lv[e] = bflo(uv.x); lv[e+1] = bfhi(uv.x); lv[e+2] = bflo(uv.y); lv[e+3] = bfhi(uv.y);
        }
        __syncthreads();

        // scores for s = c*16 .. c*16+15 (wave-uniform s -> lk reads broadcast)
        float sc[16];
        #pragma unroll
        for (int si = 0; si < 16; ++si) {
            const float4* krow = reinterpret_cast<const float4*>(&lk[(c * 16 + si) * D]);
            float a = 0.f;
            #pragma unroll
            for (int i4 = 0; i4 < 16; ++i4) {
                float4 kv = krow[i4];
                a += kv.x*qreg[4*i4] + kv.y*qreg[4*i4+1] + kv.z*qreg[4*i4+2] + kv.w*qreg[4*i4+3];
            }
            sc[si] = a;
        }
        if (st == qt) {
            #pragma unroll
            for (int si = 0; si < 16; ++si)
                if (c * 16 + si > r) sc[si] = -1e30f;
        }
        float mc = sc[0];
        #pragma unroll
        for (int si = 1; si < 16; ++si) mc = fmaxf(mc, sc[si]);
        redm[r * 5 + c] = mc;
        __syncthreads();
        float mt = fmaxf(fmaxf(redm[r*5+0], redm[r*5+1]), fmaxf(redm[r*5+2], redm[r*5+3]));
        float m_new = fmaxf(m_old, mt);
        float lc = 0.f;
        #pragma unroll
        for (int si = 0; si < 16; ++si) { sc[si] = __expf(sc[si] - m_new); lc += sc[si]; }
        redl[r * 5 + c] = lc;
        #pragma unroll
        for (int si = 0; si < 16; ++si) lp[r * 65 + c * 16 + si] = sc[si];
        __syncthreads();
        float lt = redl[r*5+0] + redl[r*5+1] + redl[r*5+2] + redl[r*5+3];
        float alpha = __expf(m_old - m_new);   // first iter: exp(-1e30)=0
        l_old = alpha * l_old + lt;
        m_old = m_new;
        #pragma unroll
        for (int d = 0; d < 16; ++d) oacc[d] *= alpha;

        // PV: this thread owns o[r][c*16 .. c*16+15]
        #pragma unroll 4
        for (int s = 0; s < 64; ++s) {
            float pv = lp[r * 65 + s];                       // 2 lanes/bank: free
            const float4* vr = reinterpret_cast<const float4*>(&lv[s * D + c * 16]);
            float4 a0 = vr[0], a1 = vr[1], a2 = vr[2], a3 = vr[3];  // broadcast
            oacc[0] += pv*a0.x; oacc[1] += pv*a0.y; oacc[2] += pv*a0.z; oacc[3] += pv*a0.w;
            oacc[4] += pv*a1.x; oacc[5] += pv*a1.y; oacc[6] += pv*a1.z; oacc[7] += pv*a1.w;
            oacc[8] += pv*a2.x; oacc[9] += pv*a2.y; oacc[10]+= pv*a2.z; oacc[11]+= pv*a2.w;
            oacc[12]+= pv*a3.x; oacc[13]+= pv*a3.y; oacc[14]+= pv*a3.z; oacc[15]+= pv*a3.w;
        }
    }
    const float inv_l = 1.0f / l_old;
    float* op = out + ((size_t)(b * T + tq) * H + h) * D + c * 16;
    float4 o0 = make_float4(oacc[0]*inv_l, oacc[1]*inv_l, oacc[2]*inv_l, oacc[3]*inv_l);
    float4 o1 = make_float4(oacc[4]*inv_l, oacc[5]*inv_l, oacc[6]*inv_l, oacc[7]*inv_l);
    float4 o2 = make_float4(oacc[8]*inv_l, oacc[9]*inv_l, oacc[10]*inv_l, oacc[11]*inv_l);
    float4 o3 = make_float4(oacc[12]*inv_l, oacc[13]*inv_l, oacc[14]*inv_l, oacc[15]*inv_l);
    reinterpret_cast<float4*>(op)[0] = o0;
    reinterpret_cast<float4*>(op)[1] = o1;
    reinterpret_cast<float4*>(op)[2] = o2;
    reinterpret_cast<float4*>(op)[3] = o3;
}

extern "C" void kernel_launch(void* const* d_in, const int* in_sizes, int n_in,
                              void* d_out, int out_size, void* d_ws, size_t ws_size,
                              hipStream_t stream) {
    const float* x   = (const float*)d_in[0];   // [B,T,K,N,D] fp32
    const float* W   = (const float*)d_in[1];   // [K,N,D,3D] fp32
    const int*   s2h = (const int*)d_in[2];     // [K,N] int32
    // d_in[3] = head_to_stream: not needed (routing folded via inverse identity)
    float* out = (float*)d_out;                 // [B,T,K,N,D] fp32

    bf16* qw = (bf16*)d_ws;                     // [B*H, T, D] each, bf16
    bf16* kw = qw + (size_t)B * H * T * D;
    bf16* vw = kw + (size_t)B * H * T * D;

    proj_kernel<<<dim3(T / 64, B * H), 192, 0, stream>>>(x, W, s2h, qw, kw, vw);
    attn_kernel<<<dim3((T / 64) * (B * H)), 256, 0, stream>>>(qw, kw, vw, out);
}

// Round 3
// 122.421 us; speedup vs baseline: 4.5784x; 4.5784x over previous
//
#include <hip/hip_runtime.h>

using f32x4 = __attribute__((ext_vector_type(4))) float;
using s16x8 = __attribute__((ext_vector_type(8))) short;

constexpr int B = 4, T = 1024, Kk = 3, Nn = 4, H = 12, D = 64;
constexpr int LDK = 72;   // LDS row stride in bf16 elems: 144B -> worst 2-way bank aliasing (free)

__device__ __forceinline__ short f2bf(float f) {
    unsigned u = __float_as_uint(f);
    u = (u + 0x7fffu + ((u >> 16) & 1u)) >> 16;   // RNE
    return (short)u;
}

// ---------------------------------------------------------------------------
// Kernel 1: routed QKV projection, MFMA.
// qkv[b,t,k,n,:] = x[b,t,k,n,:] @ Wqkv[k, s2h[k,n], :, :]
// q,k -> [bh][T][64] bf16 ; v -> TRANSPOSED [bh][64][T] bf16.
// ---------------------------------------------------------------------------
__global__ __launch_bounds__(256) void proj_kernel(
    const float* __restrict__ x, const float* __restrict__ W,
    const int* __restrict__ s2h,
    short* __restrict__ qw, short* __restrict__ kw, short* __restrict__ vt)
{
    __shared__ short ax[64 * LDK];    //  9216 B : x tile  [t_loc][i]
    __shared__ short wt[192 * LDK];   // 27648 B : W^T     [o][i]
    const int h = blockIdx.y;
    const int kk = h / Nn;
    const int m = s2h[h];
    const float* Wp = W + (size_t)(kk * Nn + m) * D * 192;
    const int tid = threadIdx.x;
    const int t0g = blockIdx.x * 64;          // global row in [0, B*T)
    const int b = t0g / T, t0 = t0g % T;
    const int bh = b * H + h;

    const float* xp = x + ((size_t)(b * T + t0) * H + h) * D;
    for (int e4 = tid; e4 < 64 * 16; e4 += 256) {
        int row = e4 >> 4, i4 = e4 & 15;
        float4 v = *reinterpret_cast<const float4*>(xp + (size_t)row * H * D + i4 * 4);
        *reinterpret_cast<short4*>(&ax[row * LDK + i4 * 4]) =
            make_short4(f2bf(v.x), f2bf(v.y), f2bf(v.z), f2bf(v.w));
    }
    for (int e4 = tid; e4 < 64 * 48; e4 += 256) {
        int i = e4 / 48, o0 = (e4 % 48) * 4;
        float4 v = *reinterpret_cast<const float4*>(Wp + (size_t)i * 192 + o0);
        wt[(o0 + 0) * LDK + i] = f2bf(v.x);
        wt[(o0 + 1) * LDK + i] = f2bf(v.y);
        wt[(o0 + 2) * LDK + i] = f2bf(v.z);
        wt[(o0 + 3) * LDK + i] = f2bf(v.w);
    }
    __syncthreads();

    const int wv = tid >> 6, lane = tid & 63, quad = lane >> 4, c = lane & 15;
    s16x8 af[4][2];
    #pragma unroll
    for (int mb = 0; mb < 4; ++mb)
        #pragma unroll
        for (int ks = 0; ks < 2; ++ks)
            af[mb][ks] = *reinterpret_cast<const s16x8*>(
                &ax[(mb * 16 + c) * LDK + ks * 32 + quad * 8]);

    f32x4 acc[4][3];
    #pragma unroll
    for (int mb = 0; mb < 4; ++mb)
        #pragma unroll
        for (int nb = 0; nb < 3; ++nb)
            acc[mb][nb] = (f32x4){0.f, 0.f, 0.f, 0.f};

    #pragma unroll
    for (int nb = 0; nb < 3; ++nb) {
        const int o16 = wv * 3 + nb;
        #pragma unroll
        for (int ks = 0; ks < 2; ++ks) {
            s16x8 bf = *reinterpret_cast<const s16x8*>(
                &wt[(o16 * 16 + c) * LDK + ks * 32 + quad * 8]);
            #pragma unroll
            for (int mb = 0; mb < 4; ++mb)
                acc[mb][nb] = __builtin_amdgcn_mfma_f32_16x16x32_bf16(
                    af[mb][ks], bf, acc[mb][nb], 0, 0, 0);
        }
    }

    #pragma unroll
    for (int nb = 0; nb < 3; ++nb) {
        const int o = (wv * 3 + nb) * 16 + c;
        const int part = o >> 6, d = o & 63;
        #pragma unroll
        for (int mb = 0; mb < 4; ++mb) {
            #pragma unroll
            for (int reg = 0; reg < 4; ++reg) {
                const int t = t0 + mb * 16 + quad * 4 + reg;
                const short val = f2bf(acc[mb][nb][reg]);
                if (part == 0)      qw[((size_t)bh * T + t) * D + d] = val;
                else if (part == 1) kw[((size_t)bh * T + t) * D + d] = val;
                else                vt[((size_t)bh * D + d) * T + t] = val;
            }
        }
    }
}

// ---------------------------------------------------------------------------
// Kernel 2: causal flash attention, MFMA. Block = 4 waves; wave w owns q-rows
// [qt*64 + w*16, +16). Online softmax in-register on the C-layout
// (row = quad*4+reg, col = lane&15); P roundtrips through wave-private LDS.
// ---------------------------------------------------------------------------
__global__ __launch_bounds__(256) void attn_kernel(
    const short* __restrict__ qw, const short* __restrict__ kw,
    const short* __restrict__ vt, float* __restrict__ out)
{
    __shared__ short lk[64 * LDK];        // K tile  [s][d]
    __shared__ short lv[64 * LDK];        // V^T tile [d][s]
    __shared__ short lp[4][16 * LDK];     // P, wave-private [r][s]

    const int idx = blockIdx.x;
    const int bh = idx % (B * H);
    const int qi = idx / (B * H);
    const int qt = (qi & 1) ? (qi >> 1) : (15 - (qi >> 1));  // load-balance perm
    const int b = bh / H, h = bh % H;
    const int tid = threadIdx.x, wv = tid >> 6, lane = tid & 63;
    const int quad = lane >> 4, c = lane & 15;
    const int tq0 = qt * 64;

    s16x8 qf[2];
    {
        const short* qp = qw + ((size_t)bh * T + tq0 + wv * 16 + c) * D;
        qf[0] = *reinterpret_cast<const s16x8*>(qp + quad * 8);
        qf[1] = *reinterpret_cast<const s16x8*>(qp + 32 + quad * 8);
    }

    f32x4 oacc[4];
    #pragma unroll
    for (int cb = 0; cb < 4; ++cb) oacc[cb] = (f32x4){0.f, 0.f, 0.f, 0.f};
    float m_run[4], l_run[4];
    #pragma unroll
    for (int r = 0; r < 4; ++r) { m_run[r] = -1e30f; l_run[r] = 0.f; }

    for (int st = 0; st <= qt; ++st) {
        __syncthreads();   // prev iter's MFMA reads of lk/lv done before restaging
        const short* kp = kw + ((size_t)bh * T + st * 64) * D;
        const short* vp = vt + (size_t)bh * D * T + st * 64;
        for (int e8 = tid; e8 < 512; e8 += 256) {
            const int row = e8 >> 3, c8 = e8 & 7;
            *reinterpret_cast<uint4*>(&lk[row * LDK + c8 * 8]) =
                *reinterpret_cast<const uint4*>(kp + (size_t)row * D + c8 * 8);
            *reinterpret_cast<uint4*>(&lv[row * LDK + c8 * 8]) =
                *reinterpret_cast<const uint4*>(vp + (size_t)row * T + c8 * 8);
        }
        __syncthreads();

        // S = Q K^T. B-frag: B[k][n] = K[s=cb*16+n][d=k].
        f32x4 sacc[4];
        #pragma unroll
        for (int cb = 0; cb < 4; ++cb) sacc[cb] = (f32x4){0.f, 0.f, 0.f, 0.f};
        #pragma unroll
        for (int ks = 0; ks < 2; ++ks) {
            #pragma unroll
            for (int cb = 0; cb < 4; ++cb) {
                s16x8 bf = *reinterpret_cast<const s16x8*>(
                    &lk[(cb * 16 + c) * LDK + ks * 32 + quad * 8]);
                sacc[cb] = __builtin_amdgcn_mfma_f32_16x16x32_bf16(
                    qf[ks], bf, sacc[cb], 0, 0, 0);
            }
        }

        // scale + causal mask
        float ps[4][4];
        #pragma unroll
        for (int cb = 0; cb < 4; ++cb)
            #pragma unroll
            for (int reg = 0; reg < 4; ++reg) {
                float s = sacc[cb][reg] * 0.125f;
                if (st == qt) {
                    const int col = st * 64 + cb * 16 + c;
                    const int row = tq0 + wv * 16 + quad * 4 + reg;
                    if (col > row) s = -1e30f;
                }
                ps[cb][reg] = s;
            }

        // online softmax (each row lives in a 16-lane quad)
        float mx[4];
        #pragma unroll
        for (int reg = 0; reg < 4; ++reg)
            mx[reg] = fmaxf(fmaxf(ps[0][reg], ps[1][reg]), fmaxf(ps[2][reg], ps[3][reg]));
        #pragma unroll
        for (int off = 1; off <= 8; off <<= 1)
            #pragma unroll
            for (int reg = 0; reg < 4; ++reg)
                mx[reg] = fmaxf(mx[reg], __shfl_xor(mx[reg], off));

        float alpha[4], lsum[4];
        #pragma unroll
        for (int reg = 0; reg < 4; ++reg) {
            const float m_new = fmaxf(m_run[reg], mx[reg]);
            alpha[reg] = __expf(m_run[reg] - m_new);
            m_run[reg] = m_new;
            lsum[reg] = 0.f;
        }
        #pragma unroll
        for (int cb = 0; cb < 4; ++cb)
            #pragma unroll
            for (int reg = 0; reg < 4; ++reg) {
                const float p = __expf(ps[cb][reg] - m_run[reg]);
                ps[cb][reg] = p;
                lsum[reg] += p;
                lp[wv][(quad * 4 + reg) * LDK + cb * 16 + c] = f2bf(p);
            }
        #pragma unroll
        for (int off = 1; off <= 8; off <<= 1)
            #pragma unroll
            for (int reg = 0; reg < 4; ++reg)
                lsum[reg] += __shfl_xor(lsum[reg], off);
        #pragma unroll
        for (int reg = 0; reg < 4; ++reg)
            l_run[reg] = alpha[reg] * l_run[reg] + lsum[reg];
        #pragma unroll
        for (int cb = 0; cb < 4; ++cb)
            #pragma unroll
            for (int reg = 0; reg < 4; ++reg)
                oacc[cb][reg] *= alpha[reg];

        // O += P V. Same-wave DS ops are in-order: no barrier needed for lp.
        // A[m][k] = P[r=m][s=k]; B[k][n] = V[s=k][d=cb*16+n] = lv[d][s].
        #pragma unroll
        for (int ks = 0; ks < 2; ++ks) {
            s16x8 af = *reinterpret_cast<const s16x8*>(
                &lp[wv][c * LDK + ks * 32 + quad * 8]);
            #pragma unroll
            for (int cb = 0; cb < 4; ++cb) {
                s16x8 bf = *reinterpret_cast<const s16x8*>(
                    &lv[(cb * 16 + c) * LDK + ks * 32 + quad * 8]);
                oacc[cb] = __builtin_amdgcn_mfma_f32_16x16x32_bf16(
                    af, bf, oacc[cb], 0, 0, 0);
            }
        }
    }

    float inv_l[4];
    #pragma unroll
    for (int reg = 0; reg < 4; ++reg) inv_l[reg] = 1.0f / l_run[reg];
    #pragma unroll
    for (int cb = 0; cb < 4; ++cb)
        #pragma unroll
        for (int reg = 0; reg < 4; ++reg) {
            const int t = tq0 + wv * 16 + quad * 4 + reg;
            const int d = cb * 16 + c;
            out[((size_t)(b * T + t) * H + h) * D + d] = oacc[cb][reg] * inv_l[reg];
        }
}

extern "C" void kernel_launch(void* const* d_in, const int* in_sizes, int n_in,
                              void* d_out, int out_size, void* d_ws, size_t ws_size,
                              hipStream_t stream) {
    const float* x   = (const float*)d_in[0];   // [B,T,K,N,D] fp32
    const float* W   = (const float*)d_in[1];   // [K,N,D,3D] fp32
    const int*   s2h = (const int*)d_in[2];     // [K,N] int32
    float* out = (float*)d_out;                 // [B,T,K,N,D] fp32

    short* qw = (short*)d_ws;                   // [bh][T][64] bf16
    short* kw = qw + (size_t)B * H * T * D;     // [bh][T][64] bf16
    short* vt = kw + (size_t)B * H * T * D;     // [bh][64][T] bf16 (transposed)

    proj_kernel<<<dim3(B * T / 64, H), 256, 0, stream>>>(x, W, s2h, qw, kw, vt);
    attn_kernel<<<dim3((T / 64) * (B * H)), 256, 0, stream>>>(qw, kw, vt, out);
}

// Round 4
// 119.684 us; speedup vs baseline: 4.6831x; 1.0229x over previous
//
#include <hip/hip_runtime.h>

using f32x4 = __attribute__((ext_vector_type(4))) float;
using s16x8 = __attribute__((ext_vector_type(8))) short;

constexpr int B = 4, T = 1024, H = 12, D = 64;
constexpr int LDK = 72;    // K/x/w LDS row stride (bf16): 144B -> 2-way bank aliasing (free)
constexpr int LDV = 136;   // V^T / P LDS row stride: 272B -> 2-way (free), 16B aligned

__device__ __forceinline__ short f2bf(float f) {        // RNE
    unsigned u = __float_as_uint(f);
    u = (u + 0x7fffu + ((u >> 16) & 1u)) >> 16;
    return (short)u;
}
__device__ __forceinline__ short f2bf_trunc(float f) {  // truncate (for P in [0,1])
    return (short)(__float_as_uint(f) >> 16);
}

// ---------------------------------------------------------------------------
// Kernel 0: one-time W prep. wt_ws[kn][o][i] = W[kn][i][o] * (o<64 ? 0.125*log2e : 1)
// (bf16, transposed, q-scale + base-2 conversion folded into Wq)
// ---------------------------------------------------------------------------
__global__ __launch_bounds__(256) void wprep_kernel(
    const float* __restrict__ W, const int* __restrict__ s2h,
    short* __restrict__ wt_ws)
{
    const int h = blockIdx.x;              // output head 0..11
    const int kk = h >> 2;
    const int m = s2h[h];                  // routed stream for this head
    const float* Wp = W + (size_t)(kk * 4 + m) * D * 192;
    short* op = wt_ws + (size_t)h * 192 * D;
    const float qs = 0.125f * 1.44269504f;
    for (int e = threadIdx.x; e < 192 * D; e += 256) {
        const int o = e >> 6, i = e & 63;
        float v = Wp[(size_t)i * 192 + o];
        if (o < 64) v *= qs;
        op[o * 64 + i] = f2bf(v);
    }
}

// ---------------------------------------------------------------------------
// Kernel 1: routed QKV projection, MFMA.
// q -> TRANSPOSED [bh][64][T] (pre-scaled by 0.125*log2e), k -> [bh][T][64],
// v -> TRANSPOSED [bh][64][T]. All bf16.
// Wave w handles o16 groups {w, w+4, w+8}: one q, one k, one v group each.
// ---------------------------------------------------------------------------
__global__ __launch_bounds__(256) void proj_kernel(
    const float* __restrict__ x, const short* __restrict__ wt_ws,
    short* __restrict__ qt, short* __restrict__ kw, short* __restrict__ vt)
{
    __shared__ short ax[64 * LDK];    //  9216 B : x tile  [t_loc][i]
    __shared__ short wt[192 * LDK];   // 27648 B : W^T     [o][i]
    const int h = blockIdx.y;
    const int tid = threadIdx.x;
    const int t0g = blockIdx.x * 64;
    const int b = t0g / T, t0 = t0g % T;
    const int bh = b * H + h;

    // stage x (fp32 -> bf16)
    const float* xp = x + ((size_t)(b * T + t0) * H + h) * D;
    for (int e4 = tid; e4 < 64 * 16; e4 += 256) {
        const int row = e4 >> 4, i4 = e4 & 15;
        float4 v = *reinterpret_cast<const float4*>(xp + (size_t)row * H * D + i4 * 4);
        *reinterpret_cast<short4*>(&ax[row * LDK + i4 * 4]) =
            make_short4(f2bf(v.x), f2bf(v.y), f2bf(v.z), f2bf(v.w));
    }
    // stage W^T (already bf16, contiguous)
    const short* wtp = wt_ws + (size_t)h * 192 * D;
    for (int e8 = tid; e8 < 192 * 8; e8 += 256) {
        const int row = e8 >> 3, c8 = e8 & 7;
        *reinterpret_cast<uint4*>(&wt[row * LDK + c8 * 8]) =
            *reinterpret_cast<const uint4*>(wtp + (size_t)row * 64 + c8 * 8);
    }
    __syncthreads();

    const int wv = tid >> 6, lane = tid & 63, quad = lane >> 4, c = lane & 15;
    s16x8 af[4][2];
    #pragma unroll
    for (int mb = 0; mb < 4; ++mb)
        #pragma unroll
        for (int ks = 0; ks < 2; ++ks)
            af[mb][ks] = *reinterpret_cast<const s16x8*>(
                &ax[(mb * 16 + c) * LDK + ks * 32 + quad * 8]);

    f32x4 acc[4][3];
    #pragma unroll
    for (int mb = 0; mb < 4; ++mb)
        #pragma unroll
        for (int nb = 0; nb < 3; ++nb)
            acc[mb][nb] = (f32x4){0.f, 0.f, 0.f, 0.f};

    #pragma unroll
    for (int nb = 0; nb < 3; ++nb) {
        const int o16 = nb * 4 + wv;             // nb=0:q, 1:k, 2:v for every wave
        #pragma unroll
        for (int ks = 0; ks < 2; ++ks) {
            s16x8 bf = *reinterpret_cast<const s16x8*>(
                &wt[(o16 * 16 + c) * LDK + ks * 32 + quad * 8]);
            #pragma unroll
            for (int mb = 0; mb < 4; ++mb)
                acc[mb][nb] = __builtin_amdgcn_mfma_f32_16x16x32_bf16(
                    af[mb][ks], bf, acc[mb][nb], 0, 0, 0);
        }
    }

    // epilogue: C-layout row = quad*4+reg (t), col = c (within o16 group)
    const int d = wv * 16 + c;                   // d index within its part
    #pragma unroll
    for (int mb = 0; mb < 4; ++mb) {
        const int t = t0 + mb * 16 + quad * 4;   // 4 consecutive t along reg
        // q: transposed [bh][d][t], contiguous along reg -> b64
        {
            short4 s = make_short4(f2bf(acc[mb][0][0]), f2bf(acc[mb][0][1]),
                                   f2bf(acc[mb][0][2]), f2bf(acc[mb][0][3]));
            *reinterpret_cast<short4*>(qt + ((size_t)bh * 64 + d) * T + t) = s;
        }
        // k: row-major [bh][t][d], scalar stores
        #pragma unroll
        for (int reg = 0; reg < 4; ++reg)
            kw[((size_t)bh * T + t + reg) * D + d] = f2bf(acc[mb][1][reg]);
        // v: transposed [bh][d][t] -> b64
        {
            short4 s = make_short4(f2bf(acc[mb][2][0]), f2bf(acc[mb][2][1]),
                                   f2bf(acc[mb][2][2]), f2bf(acc[mb][2][3]));
            *reinterpret_cast<short4*>(vt + ((size_t)bh * 64 + d) * T + t) = s;
        }
    }
}

// ---------------------------------------------------------------------------
// Kernel 2: causal flash attention, MFMA, 128-wide K-chunks, base-2 softmax.
// Block = 4 waves; wave w owns q-rows [qt*64 + w*16, +16).
// ---------------------------------------------------------------------------
__global__ __launch_bounds__(256) void attn_kernel(
    const short* __restrict__ qt_ws, const short* __restrict__ kw,
    const short* __restrict__ vt, float* __restrict__ out)
{
    __shared__ short lk[128 * LDK];       // 18432 B : K chunk  [s][d]
    __shared__ short lv[64 * LDV];        // 17408 B : V^T chunk [d][s]
    __shared__ short lp[4][16 * LDV];     // 17408 B : P, wave-private [r][s]

    const int idx = blockIdx.x;
    const int bh = idx % (B * H);
    const int qi = idx / (B * H);
    const int qtile = (qi & 1) ? (qi >> 1) : (15 - (qi >> 1));   // load balance
    const int b = bh / H, h = bh % H;
    const int tid = threadIdx.x, wv = tid >> 6, lane = tid & 63;
    const int quad = lane >> 4, c = lane & 15;
    const int tq0 = qtile * 64;

    // Q fragment: A[m=c][k=d]; q stored transposed+pre-scaled: 16 strided reads (once)
    short qfr[2][8];
    #pragma unroll
    for (int ks = 0; ks < 2; ++ks)
        #pragma unroll
        for (int j = 0; j < 8; ++j)
            qfr[ks][j] = qt_ws[((size_t)bh * 64 + ks * 32 + quad * 8 + j) * T
                               + tq0 + wv * 16 + c];
    s16x8 qf[2];
    qf[0] = *reinterpret_cast<const s16x8*>(qfr[0]);
    qf[1] = *reinterpret_cast<const s16x8*>(qfr[1]);

    f32x4 oacc[4];
    #pragma unroll
    for (int cb = 0; cb < 4; ++cb) oacc[cb] = (f32x4){0.f, 0.f, 0.f, 0.f};
    float m_run[4], l_run[4];
    #pragma unroll
    for (int r = 0; r < 4; ++r) { m_run[r] = -1e30f; l_run[r] = 0.f; }

    const int nch = (qtile + 2) >> 1;     // ceil((qtile+1)*64 / 128)
    for (int ch = 0; ch < nch; ++ch) {
        __syncthreads();
        const short* kp = kw + ((size_t)bh * T + ch * 128) * D;
        const short* vp = vt + (size_t)bh * 64 * T + ch * 128;
        for (int e8 = tid; e8 < 1024; e8 += 256) {
            const int r = e8 >> 3, c8 = e8 & 7;
            *reinterpret_cast<uint4*>(&lk[r * LDK + c8 * 8]) =
                *reinterpret_cast<const uint4*>(kp + (size_t)r * D + c8 * 8);
        }
        for (int e8 = tid; e8 < 1024; e8 += 256) {
            const int r = e8 >> 4, c8 = e8 & 15;
            *reinterpret_cast<uint4*>(&lv[r * LDV + c8 * 8]) =
                *reinterpret_cast<const uint4*>(vp + (size_t)r * T + c8 * 8);
        }
        __syncthreads();

        // S' = (log2e/8)·QK^T via pre-scaled Q. 8 col-blocks x 2 k-steps.
        f32x4 sacc[8];
        #pragma unroll
        for (int cb = 0; cb < 8; ++cb) sacc[cb] = (f32x4){0.f, 0.f, 0.f, 0.f};
        #pragma unroll
        for (int ks = 0; ks < 2; ++ks)
            #pragma unroll
            for (int cb = 0; cb < 8; ++cb) {
                s16x8 bf = *reinterpret_cast<const s16x8*>(
                    &lk[(cb * 16 + c) * LDK + ks * 32 + quad * 8]);
                sacc[cb] = __builtin_amdgcn_mfma_f32_16x16x32_bf16(
                    qf[ks], bf, sacc[cb], 0, 0, 0);
            }

        // causal mask (only the diagonal chunk can violate causality)
        if (ch == nch - 1) {
            #pragma unroll
            for (int cb = 0; cb < 8; ++cb)
                #pragma unroll
                for (int reg = 0; reg < 4; ++reg) {
                    const int col = ch * 128 + cb * 16 + c;
                    const int row = tq0 + wv * 16 + quad * 4 + reg;
                    if (col > row) sacc[cb][reg] = -1e30f;
                }
        }

        // online softmax, base-2 domain. rows live in 16-lane groups.
        float mx[4];
        #pragma unroll
        for (int reg = 0; reg < 4; ++reg) {
            float m0 = fmaxf(fmaxf(sacc[0][reg], sacc[1][reg]),
                             fmaxf(sacc[2][reg], sacc[3][reg]));
            float m1 = fmaxf(fmaxf(sacc[4][reg], sacc[5][reg]),
                             fmaxf(sacc[6][reg], sacc[7][reg]));
            mx[reg] = fmaxf(m0, m1);
        }
        #pragma unroll
        for (int off = 1; off <= 8; off <<= 1)
            #pragma unroll
            for (int reg = 0; reg < 4; ++reg)
                mx[reg] = fmaxf(mx[reg], __shfl_xor(mx[reg], off));

        float alpha[4], lsum[4];
        #pragma unroll
        for (int reg = 0; reg < 4; ++reg) {
            const float m_new = fmaxf(m_run[reg], mx[reg]);
            alpha[reg] = __builtin_amdgcn_exp2f(m_run[reg] - m_new);
            m_run[reg] = m_new;
            lsum[reg] = 0.f;
        }
        #pragma unroll
        for (int cb = 0; cb < 8; ++cb)
            #pragma unroll
            for (int reg = 0; reg < 4; ++reg) {
                const float p = __builtin_amdgcn_exp2f(sacc[cb][reg] - m_run[reg]);
                lsum[reg] += p;
                lp[wv][(quad * 4 + reg) * LDV + cb * 16 + c] = f2bf_trunc(p);
            }
        #pragma unroll
        for (int off = 1; off <= 8; off <<= 1)
            #pragma unroll
            for (int reg = 0; reg < 4; ++reg)
                lsum[reg] += __shfl_xor(lsum[reg], off);
        #pragma unroll
        for (int reg = 0; reg < 4; ++reg)
            l_run[reg] = alpha[reg] * l_run[reg] + lsum[reg];
        #pragma unroll
        for (int cb = 0; cb < 4; ++cb)
            #pragma unroll
            for (int reg = 0; reg < 4; ++reg)
                oacc[cb][reg] *= alpha[reg];

        // O += P V. Same-wave DS ops in-order: no barrier for lp.
        #pragma unroll
        for (int ks2 = 0; ks2 < 4; ++ks2) {
            s16x8 af = *reinterpret_cast<const s16x8*>(
                &lp[wv][c * LDV + ks2 * 32 + quad * 8]);
            #pragma unroll
            for (int cb = 0; cb < 4; ++cb) {
                s16x8 bf = *reinterpret_cast<const s16x8*>(
                    &lv[(cb * 16 + c) * LDV + ks2 * 32 + quad * 8]);
                oacc[cb] = __builtin_amdgcn_mfma_f32_16x16x32_bf16(
                    af, bf, oacc[cb], 0, 0, 0);
            }
        }
    }

    float inv_l[4];
    #pragma unroll
    for (int reg = 0; reg < 4; ++reg) inv_l[reg] = 1.0f / l_run[reg];
    #pragma unroll
    for (int cb = 0; cb < 4; ++cb)
        #pragma unroll
        for (int reg = 0; reg < 4; ++reg) {
            const int t = tq0 + wv * 16 + quad * 4 + reg;
            const int d = cb * 16 + c;
            out[((size_t)(b * T + t) * H + h) * D + d] = oacc[cb][reg] * inv_l[reg];
        }
}

extern "C" void kernel_launch(void* const* d_in, const int* in_sizes, int n_in,
                              void* d_out, int out_size, void* d_ws, size_t ws_size,
                              hipStream_t stream) {
    const float* x   = (const float*)d_in[0];   // [B,T,K,N,D] fp32
    const float* W   = (const float*)d_in[1];   // [K,N,D,3D] fp32
    const int*   s2h = (const int*)d_in[2];     // [K,N] int32
    float* out = (float*)d_out;                 // [B,T,K,N,D] fp32

    short* wt_ws = (short*)d_ws;                       // [12][192][64] bf16 W^T
    short* qt_ws = wt_ws + (size_t)12 * 192 * 64;      // [bh][64][T] bf16 (transposed, scaled)
    short* kw    = qt_ws + (size_t)B * H * 64 * T;     // [bh][T][64] bf16
    short* vt    = kw    + (size_t)B * H * T * 64;     // [bh][64][T] bf16 (transposed)

    wprep_kernel<<<dim3(H), 256, 0, stream>>>(W, s2h, wt_ws);
    proj_kernel<<<dim3(B * T / 64, H), 256, 0, stream>>>(x, wt_ws, qt_ws, kw, vt);
    attn_kernel<<<dim3((T / 64) * (B * H)), 256, 0, stream>>>(qt_ws, kw, vt, out);
}